// Round 16
// baseline (353.553 us; speedup 1.0000x reference)
//
#include <hip/hip_runtime.h>
#include <hip/hip_fp16.h>

#define FEAT 64
#define BK   64            // dst nodes per bucket == gemm tile rows
#define CAP  1536          // bucket capacity (mean 1023, +16 sigma)
#define MAXB 1024          // >= nbuck (782)
#define SEPT 16            // 256 thr * 16 = 4096 edges/chunk -> 196 chunks
#define CHUNK (256 * SEPT)
#define LG   4             // max distinct graphs per bucket (actual <= 2)
#define MAXG 132           // > NUM_GRAPHS (128)

typedef _Float16 f16;
typedef __attribute__((ext_vector_type(8))) _Float16 f16x8;
typedef __attribute__((ext_vector_type(4))) float    f32x4;

// ---------------------------------------------------------------------------
// Gemm LDS block (R10-R15-verified MFMA numerics).
// ---------------------------------------------------------------------------
struct GemmSm {
    union {
        struct { f16 Xs[64][72]; f16 Wt[64][72]; };  // staging (18,432 B)
        float Cs[4][16][68];                          // epilogue (17,408 B)
    };
    float asl[64], adl[64];
};

// 256-thread gemm tile from GLOBAL fp32 input (layer 1; proven body).
__device__ __forceinline__ void gemm_tile(
    GemmSm& sm, int row0, const float* __restrict__ xin,
    const float* __restrict__ W, const float* __restrict__ avs,
    const float* __restrict__ avd, unsigned* __restrict__ xph,
    float* __restrict__ as_, float* __restrict__ ad_, int n)
{
    const int t = threadIdx.x;
    const int lane = t & 63;
    const int wave = t >> 6;

    if (t < 64) sm.asl[t] = avs[t];
    else if (t < 128) sm.adl[t - 64] = avd[t - 64];

    for (int i = t; i < 64 * 16; i += 256) {
        const int r = i >> 4, c4 = (i & 15) << 2;
        const int gr = row0 + r;
        float4 v = make_float4(0.f, 0.f, 0.f, 0.f);
        if (gr < n) v = *(const float4*)(xin + (size_t)gr * FEAT + c4);
        sm.Xs[r][c4 + 0] = (f16)v.x; sm.Xs[r][c4 + 1] = (f16)v.y;
        sm.Xs[r][c4 + 2] = (f16)v.z; sm.Xs[r][c4 + 3] = (f16)v.w;
    }
    for (int i = t; i < 64 * 16; i += 256) {
        const int k = i >> 4, c4 = (i & 15) << 2;
        const float4 v = *(const float4*)(W + k * FEAT + c4);
        sm.Wt[c4 + 0][k] = (f16)v.x; sm.Wt[c4 + 1][k] = (f16)v.y;
        sm.Wt[c4 + 2][k] = (f16)v.z; sm.Wt[c4 + 3][k] = (f16)v.w;
    }
    __syncthreads();

    const int mrow = (wave << 4) + (lane & 15);
    const int kg = lane >> 4;
    const f16x8 a0 = *(const f16x8*)(&sm.Xs[mrow][kg * 8]);
    const f16x8 a1 = *(const f16x8*)(&sm.Xs[mrow][32 + kg * 8]);

    f32x4 acc[4];
#pragma unroll
    for (int nt = 0; nt < 4; ++nt) {
        const int ncol = nt * 16 + (lane & 15);
        const f16x8 b0 = *(const f16x8*)(&sm.Wt[ncol][kg * 8]);
        const f16x8 b1 = *(const f16x8*)(&sm.Wt[ncol][32 + kg * 8]);
        f32x4 c = {0.f, 0.f, 0.f, 0.f};
        c = __builtin_amdgcn_mfma_f32_16x16x32_f16(a0, b0, c, 0, 0, 0);
        c = __builtin_amdgcn_mfma_f32_16x16x32_f16(a1, b1, c, 0, 0, 0);
        acc[nt] = c;
    }
    __syncthreads();   // Xs/Wt reads done before Cs (alias) writes

#pragma unroll
    for (int nt = 0; nt < 4; ++nt)
#pragma unroll
        for (int reg = 0; reg < 4; ++reg)
            sm.Cs[wave][(lane >> 4) * 4 + reg][nt * 16 + (lane & 15)] = acc[nt][reg];

    for (int i = lane; i < 16 * 32; i += 64) {
        const int r = i >> 5, fp = i & 31;
        const int node = row0 + (wave << 4) + r;
        if (node < n) {
            const __half2 pk = __floats2half2_rn(sm.Cs[wave][r][2 * fp],
                                                 sm.Cs[wave][r][2 * fp + 1]);
            xph[(size_t)node * 32 + fp] = *(const unsigned*)&pk;
        }
    }
    {
        const int r = lane >> 2, q = lane & 3;
        float s1 = 0.f, s2 = 0.f;
#pragma unroll
        for (int j = 0; j < 16; ++j) {
            const int c = q * 16 + j;
            const float v = sm.Cs[wave][r][c];
            s1 += v * sm.asl[c];
            s2 += v * sm.adl[c];
        }
        s1 += __shfl_xor(s1, 1); s1 += __shfl_xor(s1, 2);
        s2 += __shfl_xor(s2, 1); s2 += __shfl_xor(s2, 2);
        const int node = row0 + (wave << 4) + r;
        if (q == 0 && node < n) { as_[node] = s1; ad_[node] = s2; }
    }
}

// ---------------------------------------------------------------------------
// D1: blocks [0,nchunks) scatter edges (LDS-staged coalesced writes);
// blocks [nchunks,+gemmTiles) gemm1. Scatter is hidden under gemm1 (R15).
// ---------------------------------------------------------------------------
__global__ __launch_bounds__(256) void scatter_gemm1_kernel(
    const int* __restrict__ src, const int* __restrict__ dst,
    int* __restrict__ bcur, unsigned* __restrict__ ebuf,
    const float* __restrict__ x, const float* __restrict__ W,
    const float* __restrict__ a_src, const float* __restrict__ a_dst,
    unsigned* __restrict__ xph, float* __restrict__ as_, float* __restrict__ ad_,
    int n, int E, int nbuck, int nchunks)
{
    __shared__ union {
        struct {
            unsigned staged[CHUNK];                 // 16 KB
            int hist[MAXB]; int lofs[MAXB]; int base[MAXB];  // 12 KB
        } s;
        GemmSm g;
    } sm;

    const int t = threadIdx.x;
    const int lane = t & 63;
    const int wave = t >> 6;

    if (blockIdx.x < (unsigned)nchunks) {
        for (int i = t; i < nbuck; i += 256) sm.s.hist[i] = 0;
        __syncthreads();

        const int e0 = blockIdx.x * CHUNK;
        const int total = min(E - e0, CHUNK);

        unsigned code[SEPT]; int bk[SEPT], rk[SEPT];
#pragma unroll
        for (int k = 0; k < SEPT; ++k) {
            const int e = e0 + t + k * 256;
            bk[k] = -1;
            if (e < E) {
                const int s_ = src[e], d = dst[e];
                bk[k] = d >> 6;
                code[k] = ((unsigned)s_ << 6) | (unsigned)(d & 63);
                rk[k] = atomicAdd(&sm.s.hist[bk[k]], 1);
            }
        }
        __syncthreads();

        // exclusive scan of hist -> lofs (wave 0, 64-wide chunks + carry)
        if (wave == 0) {
            int carry = 0;
            for (int b0 = 0; b0 < nbuck; b0 += 64) {
                const int idx = b0 + lane;
                int v = (idx < nbuck) ? sm.s.hist[idx] : 0;
                const int orig = v;
#pragma unroll
                for (int o = 1; o < 64; o <<= 1) {
                    const int u = __shfl_up(v, o);
                    if (lane >= o) v += u;
                }
                if (idx < nbuck) sm.s.lofs[idx] = v - orig + carry;
                carry += __shfl(v, 63);
            }
        }
        __syncthreads();
        for (int i = t; i < nbuck; i += 256) {
            const int hv = sm.s.hist[i];
            sm.s.base[i] = hv ? atomicAdd(&bcur[i], hv) : 0;
        }
        __syncthreads();

        // stage codes ordered by (bucket, rank); bucket id in bits [22,32)
#pragma unroll
        for (int k = 0; k < SEPT; ++k) {
            if (bk[k] >= 0)
                sm.s.staged[sm.s.lofs[bk[k]] + rk[k]] =
                    ((unsigned)bk[k] << 22) | code[k];
        }
        __syncthreads();

        // linear copy: bucket runs contiguous in LDS AND global -> coalesced
        for (int i = t; i < total; i += 256) {
            const unsigned e = sm.s.staged[i];
            const int bkt = e >> 22;
            const int pos = sm.s.base[bkt] + (i - sm.s.lofs[bkt]);
            if (pos < CAP) ebuf[(size_t)bkt * CAP + pos] = e & 0x3FFFFFu;
        }
    } else {
        gemm_tile(sm.g, (blockIdx.x - nchunks) * 64, x, W, a_src, a_dst,
                  xph, as_, ad_, n);
    }
}

// ---------------------------------------------------------------------------
// Aggregate phase B, R13 geometry (2 nodes/wave, 4 edge slots, uint4 loads,
// 32 rows in flight/wave), writing rows to an LDS h-tile. Used by D2.
// ---------------------------------------------------------------------------
__device__ __forceinline__ void agg_phaseB_to(
    const unsigned* scode, const float* sw, const int* startsL,
    const float* adb, const float* __restrict__ as_,
    const uint4* __restrict__ xph4, const float* __restrict__ bias,
    float* __restrict__ hout, int hstride, int g0, int n)
{
    const int lane = threadIdx.x & 63;
    const int wave = threadIdx.x >> 6;
    const int np = lane >> 5;
    const int q  = (lane >> 3) & 3;
    const int fo = lane & 7;

    for (int pair = wave; pair < BK / 2; pair += 8) {
        const int node = pair * 2 + np;
        const int g = g0 + node;
        const int gc = (g < n) ? g : (n - 1);
        const int st = startsL[node], en = startsL[node + 1];

        float a[8] = {0.f, 0.f, 0.f, 0.f, 0.f, 0.f, 0.f, 0.f};
        float wsum = 0.f;

        int i = st + q;
        for (; i + 12 < en; i += 16) {
            const unsigned c0 = scode[i];
            const unsigned c1 = scode[i + 4];
            const unsigned c2 = scode[i + 8];
            const unsigned c3 = scode[i + 12];
            const float w0 = sw[i], w1 = sw[i + 4], w2 = sw[i + 8], w3 = sw[i + 12];
            const uint4 x0 = xph4[(size_t)(c0 >> 6) * 8 + fo];
            const uint4 x1 = xph4[(size_t)(c1 >> 6) * 8 + fo];
            const uint4 x2 = xph4[(size_t)(c2 >> 6) * 8 + fo];
            const uint4 x3 = xph4[(size_t)(c3 >> 6) * 8 + fo];
#pragma unroll
            for (int u = 0; u < 4; ++u) {
                const uint4 xv = (u == 0) ? x0 : (u == 1) ? x1 : (u == 2) ? x2 : x3;
                const float wv = (u == 0) ? w0 : (u == 1) ? w1 : (u == 2) ? w2 : w3;
                const __half2 p0 = *(const __half2*)&xv.x;
                const __half2 p1 = *(const __half2*)&xv.y;
                const __half2 p2 = *(const __half2*)&xv.z;
                const __half2 p3 = *(const __half2*)&xv.w;
                a[0] += wv * __low2float(p0);  a[1] += wv * __high2float(p0);
                a[2] += wv * __low2float(p1);  a[3] += wv * __high2float(p1);
                a[4] += wv * __low2float(p2);  a[5] += wv * __high2float(p2);
                a[6] += wv * __low2float(p3);  a[7] += wv * __high2float(p3);
            }
            wsum += (w0 + w1) + (w2 + w3);
        }
        for (; i < en; i += 4) {
            const unsigned c0 = scode[i];
            const float w0 = sw[i];
            const uint4 xv = xph4[(size_t)(c0 >> 6) * 8 + fo];
            const __half2 p0 = *(const __half2*)&xv.x;
            const __half2 p1 = *(const __half2*)&xv.y;
            const __half2 p2 = *(const __half2*)&xv.z;
            const __half2 p3 = *(const __half2*)&xv.w;
            a[0] += w0 * __low2float(p0);  a[1] += w0 * __high2float(p0);
            a[2] += w0 * __low2float(p1);  a[3] += w0 * __high2float(p1);
            a[4] += w0 * __low2float(p2);  a[5] += w0 * __high2float(p2);
            a[6] += w0 * __low2float(p3);  a[7] += w0 * __high2float(p3);
            wsum += w0;
        }

#pragma unroll
        for (int j = 0; j < 8; ++j) {
            a[j] += __shfl_xor(a[j], 8);
            a[j] += __shfl_xor(a[j], 16);
        }
        wsum += __shfl_xor(wsum, 8);
        wsum += __shfl_xor(wsum, 16);

        float tt = as_[gc] + adb[node];
        tt = (tt >= 0.f) ? tt : 0.2f * tt;
        const float wself = __expf(tt);
        const uint4 xg = xph4[(size_t)gc * 8 + fo];
        const __half2 s0 = *(const __half2*)&xg.x;
        const __half2 s1 = *(const __half2*)&xg.y;
        const __half2 s2 = *(const __half2*)&xg.z;
        const __half2 s3 = *(const __half2*)&xg.w;
        const float dinv = 1.f / (wsum + wself);
        const float4 bA = *(const float4*)(bias + 8 * fo);
        const float4 bB = *(const float4*)(bias + 8 * fo + 4);

        if (q == 0 && g < n) {
            float4 vA, vB;
            vA.x = fmaxf((a[0] + wself * __low2float(s0))  * dinv + bA.x, 0.f);
            vA.y = fmaxf((a[1] + wself * __high2float(s0)) * dinv + bA.y, 0.f);
            vA.z = fmaxf((a[2] + wself * __low2float(s1))  * dinv + bA.z, 0.f);
            vA.w = fmaxf((a[3] + wself * __high2float(s1)) * dinv + bA.w, 0.f);
            vB.x = fmaxf((a[4] + wself * __low2float(s2))  * dinv + bB.x, 0.f);
            vB.y = fmaxf((a[5] + wself * __high2float(s2)) * dinv + bB.y, 0.f);
            vB.z = fmaxf((a[6] + wself * __low2float(s3))  * dinv + bB.z, 0.f);
            vB.w = fmaxf((a[7] + wself * __high2float(s3)) * dinv + bB.w, 0.f);
            *(float4*)(hout + (size_t)node * hstride + 8 * fo)     = vA;
            *(float4*)(hout + (size_t)node * hstride + 8 * fo + 4) = vB;
        }
    }
}

// ---------------------------------------------------------------------------
// D2: sort bucket -> aggregate layer 1 into LDS h-tile -> layer-2 gemm of
// the SAME 64 rows from LDS (bucket == gemm tile granularity).
// ---------------------------------------------------------------------------
__global__ __launch_bounds__(512) void sortagg1_gemm2_kernel(
    const int* __restrict__ bcur, unsigned* __restrict__ ebuf,
    int* __restrict__ startsG,
    const float* __restrict__ asA, const float* __restrict__ adA,
    const uint4* __restrict__ xphA, const float* __restrict__ b1,
    const float* __restrict__ W2, const float* __restrict__ asrc2,
    const float* __restrict__ adst2,
    unsigned* __restrict__ xphB, float* __restrict__ asB, float* __restrict__ adB,
    int n)
{
    __shared__ float htile[64][68];
    __shared__ union {
        struct { unsigned scode[CAP]; float sw[CAP]; int hist[BK]; int cur[BK]; } a;
        GemmSm g;
    } sm;
    __shared__ int starts[BK + 1];
    __shared__ float adb[BK];

    const int b = blockIdx.x;
    const int t = threadIdx.x;
    const int lane = t & 63, wave = t >> 6;
    const int g0 = b * BK;
    const int row0 = g0;

    if (t < BK) {
        sm.a.hist[t] = 0;
        adb[t] = (g0 + t < n) ? adA[g0 + t] : 0.f;
    }
    __syncthreads();

    int cnt = bcur[b];
    if (cnt > CAP) cnt = CAP;
    unsigned* eb = ebuf + (size_t)b * CAP;

    unsigned c[3];
#pragma unroll
    for (int k = 0; k < 3; ++k) {
        const int i = t + k * 512;
        if (i < cnt) { c[k] = eb[i]; atomicAdd(&sm.a.hist[c[k] & 63], 1); }
    }
    __syncthreads();
    if (wave == 0) {
        int v = sm.a.hist[lane];
#pragma unroll
        for (int o = 1; o < 64; o <<= 1) {
            const int u = __shfl_up(v, o);
            if (lane >= o) v += u;
        }
        starts[lane + 1] = v;
        sm.a.cur[lane] = v - sm.a.hist[lane];
        if (lane == 0) starts[0] = 0;
    }
    __syncthreads();
#pragma unroll
    for (int k = 0; k < 3; ++k) {
        const int i = t + k * 512;
        if (i < cnt) { const int p = atomicAdd(&sm.a.cur[c[k] & 63], 1); sm.a.scode[p] = c[k]; }
    }
    __syncthreads();

    unsigned cc[3]; float vv[3];
#pragma unroll
    for (int k = 0; k < 3; ++k) {
        const int i = t + k * 512;
        if (i < cnt) { cc[k] = sm.a.scode[i]; eb[i] = cc[k]; vv[k] = asA[cc[k] >> 6]; }
    }
    if (t <= BK) startsG[b * (BK + 1) + t] = starts[t];
#pragma unroll
    for (int k = 0; k < 3; ++k) {
        const int i = t + k * 512;
        if (i < cnt) {
            float tt = vv[k] + adb[cc[k] & 63];
            tt = (tt >= 0.f) ? tt : 0.2f * tt;
            sm.a.sw[i] = __expf(tt);
        }
    }
    __syncthreads();

    agg_phaseB_to(sm.a.scode, sm.a.sw, starts, adb, asA, xphA, b1,
                  &htile[0][0], 68, g0, n);
    __syncthreads();

    if (t < 64) sm.g.asl[t] = asrc2[t];
    else if (t < 128) sm.g.adl[t - 64] = adst2[t - 64];

    for (int i = t; i < 64 * 16; i += 512) {
        const int r = i >> 4, c4 = (i & 15) << 2;
        const float4 v = *(const float4*)(&htile[r][c4]);
        sm.g.Xs[r][c4 + 0] = (f16)v.x; sm.g.Xs[r][c4 + 1] = (f16)v.y;
        sm.g.Xs[r][c4 + 2] = (f16)v.z; sm.g.Xs[r][c4 + 3] = (f16)v.w;
    }
    for (int i = t; i < 64 * 16; i += 512) {
        const int k = i >> 4, c4 = (i & 15) << 2;
        const float4 v = *(const float4*)(W2 + k * FEAT + c4);
        sm.g.Wt[c4 + 0][k] = (f16)v.x; sm.g.Wt[c4 + 1][k] = (f16)v.y;
        sm.g.Wt[c4 + 2][k] = (f16)v.z; sm.g.Wt[c4 + 3][k] = (f16)v.w;
    }
    __syncthreads();

    f32x4 acc[4];
    if (wave < 4) {
        const int mrow = (wave << 4) + (lane & 15);
        const int kg = lane >> 4;
        const f16x8 a0 = *(const f16x8*)(&sm.g.Xs[mrow][kg * 8]);
        const f16x8 a1 = *(const f16x8*)(&sm.g.Xs[mrow][32 + kg * 8]);
#pragma unroll
        for (int nt = 0; nt < 4; ++nt) {
            const int ncol = nt * 16 + (lane & 15);
            const f16x8 b0 = *(const f16x8*)(&sm.g.Wt[ncol][kg * 8]);
            const f16x8 b1v = *(const f16x8*)(&sm.g.Wt[ncol][32 + kg * 8]);
            f32x4 cacc = {0.f, 0.f, 0.f, 0.f};
            cacc = __builtin_amdgcn_mfma_f32_16x16x32_f16(a0, b0, cacc, 0, 0, 0);
            cacc = __builtin_amdgcn_mfma_f32_16x16x32_f16(a1, b1v, cacc, 0, 0, 0);
            acc[nt] = cacc;
        }
    }
    __syncthreads();
    if (wave < 4) {
#pragma unroll
        for (int nt = 0; nt < 4; ++nt)
#pragma unroll
            for (int reg = 0; reg < 4; ++reg)
                sm.g.Cs[wave][(lane >> 4) * 4 + reg][nt * 16 + (lane & 15)] = acc[nt][reg];
    }
    __syncthreads();

    for (int i = t; i < 64 * 32; i += 512) {
        const int r = i >> 5, fp = i & 31;
        const int node = row0 + r;
        if (node < n) {
            const __half2 pk = __floats2half2_rn(sm.g.Cs[r >> 4][r & 15][2 * fp],
                                                 sm.g.Cs[r >> 4][r & 15][2 * fp + 1]);
            xphB[(size_t)node * 32 + fp] = *(const unsigned*)&pk;
        }
    }
    if (t < 256) {
        const int r = t >> 2, q = t & 3;
        float s1 = 0.f, s2 = 0.f;
#pragma unroll
        for (int j = 0; j < 16; ++j) {
            const int cidx = q * 16 + j;
            const float v = sm.g.Cs[r >> 4][r & 15][cidx];
            s1 += v * sm.g.asl[cidx];
            s2 += v * sm.g.adl[cidx];
        }
        s1 += __shfl_xor(s1, 1); s1 += __shfl_xor(s1, 2);
        s2 += __shfl_xor(s2, 1); s2 += __shfl_xor(s2, 2);
        const int node = row0 + r;
        if (q == 0 && node < n) { asB[node] = s1; adB[node] = s2; }
    }
}

// ---------------------------------------------------------------------------
// D3: layer-2 aggregate fused with pooling (per-bucket per-graph partials)
// AND the final reduce via last-block-done: the last finishing block
// acquires (threadfence + device atomic counter), computes all graph
// bounds in parallel, sums gpart columns, writes d_out. Removes D4.
// ---------------------------------------------------------------------------
__device__ __forceinline__ int lower_bound_i(const int* a, int n, int key)
{
    int lo = 0, hi = n;
    while (lo < hi) {
        const int mid = (lo + hi) >> 1;
        if (a[mid] < key) lo = mid + 1; else hi = mid;
    }
    return lo;
}

__global__ __launch_bounds__(512) void agg2_pool_kernel(
    const unsigned* __restrict__ ebuf, const int* __restrict__ startsG,
    const float* __restrict__ as_, const float* __restrict__ ad_,
    const uint4* __restrict__ xph4, const float* __restrict__ bias,
    const int* __restrict__ batch, float* __restrict__ gpart,
    int* __restrict__ done, float* __restrict__ out,
    int n, int G, int nbuck)
{
    __shared__ unsigned scode[CAP];
    __shared__ float    sw[CAP];
    __shared__ int startsL[BK + 1];
    __shared__ float adb[BK];
    __shared__ int batchL[BK];
    __shared__ float gpartW[8][2][LG][FEAT];   // 16 KB, lane-exclusive slots
    __shared__ int glo[MAXG];
    __shared__ int isLast;

    const int b = blockIdx.x;
    const int t = threadIdx.x;
    const int lane = t & 63, wave = t >> 6;
    const int g0 = b * BK;

    if (t < BK) {
        const int g = g0 + t;
        adb[t] = (g < n) ? ad_[g] : 0.f;
        batchL[t] = batch[(g < n) ? g : (n - 1)];
    }
    if (t <= BK) startsL[t] = startsG[b * (BK + 1) + t];
    for (int i = t; i < 8 * 2 * LG * FEAT; i += 512) ((float*)gpartW)[i] = 0.f;
    __syncthreads();

    const int cnt = startsL[BK];
    const unsigned* eb = ebuf + (size_t)b * CAP;

    unsigned cc[3]; float vv[3];
#pragma unroll
    for (int k = 0; k < 3; ++k) {
        const int i = t + k * 512;
        if (i < cnt) { cc[k] = eb[i]; vv[k] = as_[cc[k] >> 6]; }
    }
#pragma unroll
    for (int k = 0; k < 3; ++k) {
        const int i = t + k * 512;
        if (i < cnt) {
            float tt = vv[k] + adb[cc[k] & 63];
            tt = (tt >= 0.f) ? tt : 0.2f * tt;
            scode[i] = cc[k]; sw[i] = __expf(tt);
        }
    }
    __syncthreads();

    const int np = lane >> 5;
    const int q  = (lane >> 3) & 3;
    const int fo = lane & 7;
    const int gbase = batchL[0];

    for (int pair = wave; pair < BK / 2; pair += 8) {
        const int node = pair * 2 + np;
        const int g = g0 + node;
        const int gc = (g < n) ? g : (n - 1);
        const int st = startsL[node], en = startsL[node + 1];

        float a[8] = {0.f, 0.f, 0.f, 0.f, 0.f, 0.f, 0.f, 0.f};
        float wsum = 0.f;

        int i = st + q;
        for (; i + 12 < en; i += 16) {
            const unsigned c0 = scode[i];
            const unsigned c1 = scode[i + 4];
            const unsigned c2 = scode[i + 8];
            const unsigned c3 = scode[i + 12];
            const float w0 = sw[i], w1 = sw[i + 4], w2 = sw[i + 8], w3 = sw[i + 12];
            const uint4 x0 = xph4[(size_t)(c0 >> 6) * 8 + fo];
            const uint4 x1 = xph4[(size_t)(c1 >> 6) * 8 + fo];
            const uint4 x2 = xph4[(size_t)(c2 >> 6) * 8 + fo];
            const uint4 x3 = xph4[(size_t)(c3 >> 6) * 8 + fo];
#pragma unroll
            for (int u = 0; u < 4; ++u) {
                const uint4 xv = (u == 0) ? x0 : (u == 1) ? x1 : (u == 2) ? x2 : x3;
                const float wv = (u == 0) ? w0 : (u == 1) ? w1 : (u == 2) ? w2 : w3;
                const __half2 p0 = *(const __half2*)&xv.x;
                const __half2 p1 = *(const __half2*)&xv.y;
                const __half2 p2 = *(const __half2*)&xv.z;
                const __half2 p3 = *(const __half2*)&xv.w;
                a[0] += wv * __low2float(p0);  a[1] += wv * __high2float(p0);
                a[2] += wv * __low2float(p1);  a[3] += wv * __high2float(p1);
                a[4] += wv * __low2float(p2);  a[5] += wv * __high2float(p2);
                a[6] += wv * __low2float(p3);  a[7] += wv * __high2float(p3);
            }
            wsum += (w0 + w1) + (w2 + w3);
        }
        for (; i < en; i += 4) {
            const unsigned c0 = scode[i];
            const float w0 = sw[i];
            const uint4 xv = xph4[(size_t)(c0 >> 6) * 8 + fo];
            const __half2 p0 = *(const __half2*)&xv.x;
            const __half2 p1 = *(const __half2*)&xv.y;
            const __half2 p2 = *(const __half2*)&xv.z;
            const __half2 p3 = *(const __half2*)&xv.w;
            a[0] += w0 * __low2float(p0);  a[1] += w0 * __high2float(p0);
            a[2] += w0 * __low2float(p1);  a[3] += w0 * __high2float(p1);
            a[4] += w0 * __low2float(p2);  a[5] += w0 * __high2float(p2);
            a[6] += w0 * __low2float(p3);  a[7] += w0 * __high2float(p3);
            wsum += w0;
        }

#pragma unroll
        for (int j = 0; j < 8; ++j) {
            a[j] += __shfl_xor(a[j], 8);
            a[j] += __shfl_xor(a[j], 16);
        }
        wsum += __shfl_xor(wsum, 8);
        wsum += __shfl_xor(wsum, 16);

        float tt = as_[gc] + adb[node];
        tt = (tt >= 0.f) ? tt : 0.2f * tt;
        const float wself = __expf(tt);
        const uint4 xg = xph4[(size_t)gc * 8 + fo];
        const __half2 s0 = *(const __half2*)&xg.x;
        const __half2 s1 = *(const __half2*)&xg.y;
        const __half2 s2 = *(const __half2*)&xg.z;
        const __half2 s3 = *(const __half2*)&xg.w;
        const float dinv = 1.f / (wsum + wself);
        const float4 bA = *(const float4*)(bias + 8 * fo);
        const float4 bB = *(const float4*)(bias + 8 * fo + 4);

        if (q == 0 && g < n) {
            float4 vA, vB;
            vA.x = fmaxf((a[0] + wself * __low2float(s0))  * dinv + bA.x, 0.f);
            vA.y = fmaxf((a[1] + wself * __high2float(s0)) * dinv + bA.y, 0.f);
            vA.z = fmaxf((a[2] + wself * __low2float(s1))  * dinv + bA.z, 0.f);
            vA.w = fmaxf((a[3] + wself * __high2float(s1)) * dinv + bA.w, 0.f);
            vB.x = fmaxf((a[4] + wself * __low2float(s2))  * dinv + bB.x, 0.f);
            vB.y = fmaxf((a[5] + wself * __high2float(s2)) * dinv + bB.y, 0.f);
            vB.z = fmaxf((a[6] + wself * __low2float(s3))  * dinv + bB.z, 0.f);
            vB.w = fmaxf((a[7] + wself * __high2float(s3)) * dinv + bB.w, 0.f);

            const int lg = batchL[node] - gbase;
            if (lg >= 0 && lg < LG) {   // always true: min graph ~330 nodes
                float* p = &gpartW[wave][np][lg][8 * fo];
                float4 oA = *(float4*)p;
                float4 oB = *(float4*)(p + 4);
                oA.x += vA.x; oA.y += vA.y; oA.z += vA.z; oA.w += vA.w;
                oB.x += vB.x; oB.y += vB.y; oB.z += vB.z; oB.w += vB.w;
                *(float4*)p = oA;
                *(float4*)(p + 4) = oB;
            }
        }
    }
    __syncthreads();

    if (t < LG * FEAT) {
        const int lg = t >> 6, f = t & 63;
        float s = 0.f;
#pragma unroll
        for (int w = 0; w < 8; ++w)
            s += gpartW[w][0][lg][f] + gpartW[w][1][lg][f];
        gpart[((size_t)b * LG + lg) * FEAT + f] = s;
    }

    // ---- last-block pool reduce (replaces D4) ----
    __threadfence();            // release: gpart stores device-visible
    __syncthreads();
    if (t == 0) {
        const int old = atomicAdd(done, 1);
        isLast = (old == nbuck - 1);
    }
    __syncthreads();
    if (!isLast) return;
    __threadfence();            // acquire: all blocks' gpart visible

    for (int i = t; i <= G && i < MAXG; i += 512)
        glo[i] = lower_bound_i(batch, n, i);
    __syncthreads();

    for (int i = t; i < G * FEAT; i += 512) {
        const int g = i >> 6, f = i & 63;
        const int lo = glo[g], hi = glo[g + 1];
        float s = 0.f;
        if (lo < hi) {
            const int b0 = lo >> 6, b1 = (hi - 1) >> 6;
            for (int bb = b0; bb <= b1; ++bb) {
                const int lg = g - batch[bb << 6];
                if (lg >= 0 && lg < LG)
                    s += gpart[((size_t)bb * LG + lg) * FEAT + f];
            }
        }
        out[(size_t)g * FEAT + f] = s / fmaxf((float)(hi - lo), 1.f);
    }
}

extern "C" void kernel_launch(void* const* d_in, const int* in_sizes, int n_in,
                              void* d_out, int out_size, void* d_ws, size_t ws_size,
                              hipStream_t stream)
{
    const float* x      = (const float*)d_in[0];
    const int*   ei     = (const int*)d_in[1];
    const int*   batch  = (const int*)d_in[2];
    const float* W1     = (const float*)d_in[3];
    const float* asrc1  = (const float*)d_in[4];
    const float* adst1  = (const float*)d_in[5];
    const float* b1     = (const float*)d_in[6];
    const float* W2     = (const float*)d_in[7];
    const float* asrc2  = (const float*)d_in[8];
    const float* adst2  = (const float*)d_in[9];
    const float* b2     = (const float*)d_in[10];

    const int N = in_sizes[2];          // 50000 nodes
    const int E = in_sizes[1] / 2;      // 800000 edges
    const int G = out_size / FEAT;      // 128 graphs

    const int* src = ei;
    const int* dst = ei + E;

    const int nbuck   = (N + BK - 1) / BK;                  // 782
    const int nchunks = (E + CHUNK - 1) / CHUNK;            // 196
    const int gemmBlocks = (N + 63) / 64;                   // 782

    // Workspace layout (bcur|done adjacent -> one small memset)
    unsigned* xphA    = (unsigned*)d_ws;                     // N*32 u32
    unsigned* xphB    = xphA + (size_t)N * 32;               // N*32 u32
    float*    asA     = (float*)(xphB + (size_t)N * 32);     // N f
    float*    adA     = asA + N;                             // N f
    float*    asB     = adA + N;                             // N f
    float*    adB     = asB + N;                             // N f
    int*      bcur    = (int*)(adB + N);                     // nbuck i
    int*      done    = bcur + nbuck;                        // 1 i
    unsigned* ebuf    = (unsigned*)(done + 1);               // nbuck*CAP u32
    int*      startsG = (int*)(ebuf + (size_t)nbuck * CAP);  // nbuck*(BK+1) i
    float*    gpart   = (float*)(startsG + nbuck * (BK + 1));// nbuck*LG*64 f

    // D0: zero bucket cursors + done counter
    hipMemsetAsync(bcur, 0, ((size_t)nbuck + 1) * sizeof(int), stream);
    // D1: scatter (LDS-staged coalesced writes) || gemm layer 1
    scatter_gemm1_kernel<<<nchunks + gemmBlocks, 256, 0, stream>>>(
        src, dst, bcur, ebuf, x, W1, asrc1, adst1, xphA, asA, adA,
        N, E, nbuck, nchunks);
    // D2: sort + layer-1 aggregate (LDS h-tile) + layer-2 gemm (tile-aligned)
    sortagg1_gemm2_kernel<<<nbuck, 512, 0, stream>>>(
        bcur, ebuf, startsG, asA, adA, (const uint4*)xphA, b1,
        W2, asrc2, adst2, xphB, asB, adB, N);
    // D3: layer-2 aggregate + pooling partials + last-block final reduce
    agg2_pool_kernel<<<nbuck, 512, 0, stream>>>(
        ebuf, startsG, asB, adB, (const uint4*)xphB, b2,
        batch, gpart, done, (float*)d_out, N, G, nbuck);
}

// Round 17
// 176.376 us; speedup vs baseline: 2.0045x; 2.0045x over previous
//
#include <hip/hip_runtime.h>
#include <hip/hip_fp16.h>

#define FEAT 64
#define BK   64            // dst nodes per bucket == gemm tile rows
#define CAP  1536          // bucket capacity (mean 1023, +16 sigma)
#define MAXB 1024          // >= nbuck (782)
#define SEPT 16            // 256 thr * 16 = 4096 edges/chunk -> 196 chunks
#define CHUNK (256 * SEPT)
#define LG   4             // max distinct graphs per bucket (actual <= 2)

typedef _Float16 f16;
typedef __attribute__((ext_vector_type(8))) _Float16 f16x8;
typedef __attribute__((ext_vector_type(4))) float    f32x4;

// ---------------------------------------------------------------------------
// Gemm LDS block (R10-R15-verified MFMA numerics).
// NOTE (R16 lesson): device-scope __threadfence / grid.sync cost ~100x a
// dispatch boundary on gfx950 (cross-XCD L2 writeback) — never use them to
// save a launch. Dispatch boundaries ARE the cheap device-wide barrier.
// ---------------------------------------------------------------------------
struct GemmSm {
    union {
        struct { f16 Xs[64][72]; f16 Wt[64][72]; };  // staging (18,432 B)
        float Cs[4][16][68];                          // epilogue (17,408 B)
    };
    float asl[64], adl[64];
};

// 256-thread gemm tile from GLOBAL fp32 input (layer 1; proven body).
__device__ __forceinline__ void gemm_tile(
    GemmSm& sm, int row0, const float* __restrict__ xin,
    const float* __restrict__ W, const float* __restrict__ avs,
    const float* __restrict__ avd, unsigned* __restrict__ xph,
    float* __restrict__ as_, float* __restrict__ ad_, int n)
{
    const int t = threadIdx.x;
    const int lane = t & 63;
    const int wave = t >> 6;

    if (t < 64) sm.asl[t] = avs[t];
    else if (t < 128) sm.adl[t - 64] = avd[t - 64];

    for (int i = t; i < 64 * 16; i += 256) {
        const int r = i >> 4, c4 = (i & 15) << 2;
        const int gr = row0 + r;
        float4 v = make_float4(0.f, 0.f, 0.f, 0.f);
        if (gr < n) v = *(const float4*)(xin + (size_t)gr * FEAT + c4);
        sm.Xs[r][c4 + 0] = (f16)v.x; sm.Xs[r][c4 + 1] = (f16)v.y;
        sm.Xs[r][c4 + 2] = (f16)v.z; sm.Xs[r][c4 + 3] = (f16)v.w;
    }
    for (int i = t; i < 64 * 16; i += 256) {
        const int k = i >> 4, c4 = (i & 15) << 2;
        const float4 v = *(const float4*)(W + k * FEAT + c4);
        sm.Wt[c4 + 0][k] = (f16)v.x; sm.Wt[c4 + 1][k] = (f16)v.y;
        sm.Wt[c4 + 2][k] = (f16)v.z; sm.Wt[c4 + 3][k] = (f16)v.w;
    }
    __syncthreads();

    const int mrow = (wave << 4) + (lane & 15);
    const int kg = lane >> 4;
    const f16x8 a0 = *(const f16x8*)(&sm.Xs[mrow][kg * 8]);
    const f16x8 a1 = *(const f16x8*)(&sm.Xs[mrow][32 + kg * 8]);

    f32x4 acc[4];
#pragma unroll
    for (int nt = 0; nt < 4; ++nt) {
        const int ncol = nt * 16 + (lane & 15);
        const f16x8 b0 = *(const f16x8*)(&sm.Wt[ncol][kg * 8]);
        const f16x8 b1 = *(const f16x8*)(&sm.Wt[ncol][32 + kg * 8]);
        f32x4 c = {0.f, 0.f, 0.f, 0.f};
        c = __builtin_amdgcn_mfma_f32_16x16x32_f16(a0, b0, c, 0, 0, 0);
        c = __builtin_amdgcn_mfma_f32_16x16x32_f16(a1, b1, c, 0, 0, 0);
        acc[nt] = c;
    }
    __syncthreads();   // Xs/Wt reads done before Cs (alias) writes

#pragma unroll
    for (int nt = 0; nt < 4; ++nt)
#pragma unroll
        for (int reg = 0; reg < 4; ++reg)
            sm.Cs[wave][(lane >> 4) * 4 + reg][nt * 16 + (lane & 15)] = acc[nt][reg];

    for (int i = lane; i < 16 * 32; i += 64) {
        const int r = i >> 5, fp = i & 31;
        const int node = row0 + (wave << 4) + r;
        if (node < n) {
            const __half2 pk = __floats2half2_rn(sm.Cs[wave][r][2 * fp],
                                                 sm.Cs[wave][r][2 * fp + 1]);
            xph[(size_t)node * 32 + fp] = *(const unsigned*)&pk;
        }
    }
    {
        const int r = lane >> 2, q = lane & 3;
        float s1 = 0.f, s2 = 0.f;
#pragma unroll
        for (int j = 0; j < 16; ++j) {
            const int c = q * 16 + j;
            const float v = sm.Cs[wave][r][c];
            s1 += v * sm.asl[c];
            s2 += v * sm.adl[c];
        }
        s1 += __shfl_xor(s1, 1); s1 += __shfl_xor(s1, 2);
        s2 += __shfl_xor(s2, 1); s2 += __shfl_xor(s2, 2);
        const int node = row0 + (wave << 4) + r;
        if (q == 0 && node < n) { as_[node] = s1; ad_[node] = s2; }
    }
}

// ---------------------------------------------------------------------------
// D1: blocks [0,nchunks) scatter edges (LDS-staged coalesced writes);
// blocks [nchunks,+gemmTiles) gemm1. Scatter hidden under gemm1 (R15).
// ---------------------------------------------------------------------------
__global__ __launch_bounds__(256) void scatter_gemm1_kernel(
    const int* __restrict__ src, const int* __restrict__ dst,
    int* __restrict__ bcur, unsigned* __restrict__ ebuf,
    const float* __restrict__ x, const float* __restrict__ W,
    const float* __restrict__ a_src, const float* __restrict__ a_dst,
    unsigned* __restrict__ xph, float* __restrict__ as_, float* __restrict__ ad_,
    int n, int E, int nbuck, int nchunks)
{
    __shared__ union {
        struct {
            unsigned staged[CHUNK];                 // 16 KB
            int hist[MAXB]; int lofs[MAXB]; int base[MAXB];  // 12 KB
        } s;
        GemmSm g;
    } sm;

    const int t = threadIdx.x;
    const int lane = t & 63;
    const int wave = t >> 6;

    if (blockIdx.x < (unsigned)nchunks) {
        for (int i = t; i < nbuck; i += 256) sm.s.hist[i] = 0;
        __syncthreads();

        const int e0 = blockIdx.x * CHUNK;
        const int total = min(E - e0, CHUNK);

        unsigned code[SEPT]; int bk[SEPT], rk[SEPT];
#pragma unroll
        for (int k = 0; k < SEPT; ++k) {
            const int e = e0 + t + k * 256;
            bk[k] = -1;
            if (e < E) {
                const int s_ = src[e], d = dst[e];
                bk[k] = d >> 6;
                code[k] = ((unsigned)s_ << 6) | (unsigned)(d & 63);
                rk[k] = atomicAdd(&sm.s.hist[bk[k]], 1);
            }
        }
        __syncthreads();

        // exclusive scan of hist -> lofs (wave 0, 64-wide chunks + carry)
        if (wave == 0) {
            int carry = 0;
            for (int b0 = 0; b0 < nbuck; b0 += 64) {
                const int idx = b0 + lane;
                int v = (idx < nbuck) ? sm.s.hist[idx] : 0;
                const int orig = v;
#pragma unroll
                for (int o = 1; o < 64; o <<= 1) {
                    const int u = __shfl_up(v, o);
                    if (lane >= o) v += u;
                }
                if (idx < nbuck) sm.s.lofs[idx] = v - orig + carry;
                carry += __shfl(v, 63);
            }
        }
        __syncthreads();
        for (int i = t; i < nbuck; i += 256) {
            const int hv = sm.s.hist[i];
            sm.s.base[i] = hv ? atomicAdd(&bcur[i], hv) : 0;
        }
        __syncthreads();

        // stage codes ordered by (bucket, rank); bucket id in bits [22,32)
#pragma unroll
        for (int k = 0; k < SEPT; ++k) {
            if (bk[k] >= 0)
                sm.s.staged[sm.s.lofs[bk[k]] + rk[k]] =
                    ((unsigned)bk[k] << 22) | code[k];
        }
        __syncthreads();

        // linear copy: bucket runs contiguous in LDS AND global -> coalesced
        for (int i = t; i < total; i += 256) {
            const unsigned e = sm.s.staged[i];
            const int bkt = e >> 22;
            const int pos = sm.s.base[bkt] + (i - sm.s.lofs[bkt]);
            if (pos < CAP) ebuf[(size_t)bkt * CAP + pos] = e & 0x3FFFFFu;
        }
    } else {
        gemm_tile(sm.g, (blockIdx.x - nchunks) * 64, x, W, a_src, a_dst,
                  xph, as_, ad_, n);
    }
}

// ---------------------------------------------------------------------------
// Aggregate phase B, R13 geometry (2 nodes/wave, 4 edge slots, uint4 loads,
// 32 rows in flight/wave), writing rows to an LDS h-tile. Used by D2.
// ---------------------------------------------------------------------------
__device__ __forceinline__ void agg_phaseB_to(
    const unsigned* scode, const float* sw, const int* startsL,
    const float* adb, const float* __restrict__ as_,
    const uint4* __restrict__ xph4, const float* __restrict__ bias,
    float* __restrict__ hout, int hstride, int g0, int n)
{
    const int lane = threadIdx.x & 63;
    const int wave = threadIdx.x >> 6;
    const int np = lane >> 5;
    const int q  = (lane >> 3) & 3;
    const int fo = lane & 7;

    for (int pair = wave; pair < BK / 2; pair += 8) {
        const int node = pair * 2 + np;
        const int g = g0 + node;
        const int gc = (g < n) ? g : (n - 1);
        const int st = startsL[node], en = startsL[node + 1];

        float a[8] = {0.f, 0.f, 0.f, 0.f, 0.f, 0.f, 0.f, 0.f};
        float wsum = 0.f;

        int i = st + q;
        for (; i + 12 < en; i += 16) {
            const unsigned c0 = scode[i];
            const unsigned c1 = scode[i + 4];
            const unsigned c2 = scode[i + 8];
            const unsigned c3 = scode[i + 12];
            const float w0 = sw[i], w1 = sw[i + 4], w2 = sw[i + 8], w3 = sw[i + 12];
            const uint4 x0 = xph4[(size_t)(c0 >> 6) * 8 + fo];
            const uint4 x1 = xph4[(size_t)(c1 >> 6) * 8 + fo];
            const uint4 x2 = xph4[(size_t)(c2 >> 6) * 8 + fo];
            const uint4 x3 = xph4[(size_t)(c3 >> 6) * 8 + fo];
#pragma unroll
            for (int u = 0; u < 4; ++u) {
                const uint4 xv = (u == 0) ? x0 : (u == 1) ? x1 : (u == 2) ? x2 : x3;
                const float wv = (u == 0) ? w0 : (u == 1) ? w1 : (u == 2) ? w2 : w3;
                const __half2 p0 = *(const __half2*)&xv.x;
                const __half2 p1 = *(const __half2*)&xv.y;
                const __half2 p2 = *(const __half2*)&xv.z;
                const __half2 p3 = *(const __half2*)&xv.w;
                a[0] += wv * __low2float(p0);  a[1] += wv * __high2float(p0);
                a[2] += wv * __low2float(p1);  a[3] += wv * __high2float(p1);
                a[4] += wv * __low2float(p2);  a[5] += wv * __high2float(p2);
                a[6] += wv * __low2float(p3);  a[7] += wv * __high2float(p3);
            }
            wsum += (w0 + w1) + (w2 + w3);
        }
        for (; i < en; i += 4) {
            const unsigned c0 = scode[i];
            const float w0 = sw[i];
            const uint4 xv = xph4[(size_t)(c0 >> 6) * 8 + fo];
            const __half2 p0 = *(const __half2*)&xv.x;
            const __half2 p1 = *(const __half2*)&xv.y;
            const __half2 p2 = *(const __half2*)&xv.z;
            const __half2 p3 = *(const __half2*)&xv.w;
            a[0] += w0 * __low2float(p0);  a[1] += w0 * __high2float(p0);
            a[2] += w0 * __low2float(p1);  a[3] += w0 * __high2float(p1);
            a[4] += w0 * __low2float(p2);  a[5] += w0 * __high2float(p2);
            a[6] += w0 * __low2float(p3);  a[7] += w0 * __high2float(p3);
            wsum += w0;
        }

#pragma unroll
        for (int j = 0; j < 8; ++j) {
            a[j] += __shfl_xor(a[j], 8);
            a[j] += __shfl_xor(a[j], 16);
        }
        wsum += __shfl_xor(wsum, 8);
        wsum += __shfl_xor(wsum, 16);

        float tt = as_[gc] + adb[node];
        tt = (tt >= 0.f) ? tt : 0.2f * tt;
        const float wself = __expf(tt);
        const uint4 xg = xph4[(size_t)gc * 8 + fo];
        const __half2 s0 = *(const __half2*)&xg.x;
        const __half2 s1 = *(const __half2*)&xg.y;
        const __half2 s2 = *(const __half2*)&xg.z;
        const __half2 s3 = *(const __half2*)&xg.w;
        const float dinv = 1.f / (wsum + wself);
        const float4 bA = *(const float4*)(bias + 8 * fo);
        const float4 bB = *(const float4*)(bias + 8 * fo + 4);

        if (q == 0 && g < n) {
            float4 vA, vB;
            vA.x = fmaxf((a[0] + wself * __low2float(s0))  * dinv + bA.x, 0.f);
            vA.y = fmaxf((a[1] + wself * __high2float(s0)) * dinv + bA.y, 0.f);
            vA.z = fmaxf((a[2] + wself * __low2float(s1))  * dinv + bA.z, 0.f);
            vA.w = fmaxf((a[3] + wself * __high2float(s1)) * dinv + bA.w, 0.f);
            vB.x = fmaxf((a[4] + wself * __low2float(s2))  * dinv + bB.x, 0.f);
            vB.y = fmaxf((a[5] + wself * __high2float(s2)) * dinv + bB.y, 0.f);
            vB.z = fmaxf((a[6] + wself * __low2float(s3))  * dinv + bB.z, 0.f);
            vB.w = fmaxf((a[7] + wself * __high2float(s3)) * dinv + bB.w, 0.f);
            *(float4*)(hout + (size_t)node * hstride + 8 * fo)     = vA;
            *(float4*)(hout + (size_t)node * hstride + 8 * fo + 4) = vB;
        }
    }
}

// ---------------------------------------------------------------------------
// D2: sort bucket -> aggregate layer 1 into LDS h-tile -> layer-2 gemm of
// the SAME 64 rows from LDS (bucket == gemm tile granularity).
// ---------------------------------------------------------------------------
__global__ __launch_bounds__(512) void sortagg1_gemm2_kernel(
    const int* __restrict__ bcur, unsigned* __restrict__ ebuf,
    int* __restrict__ startsG,
    const float* __restrict__ asA, const float* __restrict__ adA,
    const uint4* __restrict__ xphA, const float* __restrict__ b1,
    const float* __restrict__ W2, const float* __restrict__ asrc2,
    const float* __restrict__ adst2,
    unsigned* __restrict__ xphB, float* __restrict__ asB, float* __restrict__ adB,
    int n)
{
    __shared__ float htile[64][68];
    __shared__ union {
        struct { unsigned scode[CAP]; float sw[CAP]; int hist[BK]; int cur[BK]; } a;
        GemmSm g;
    } sm;
    __shared__ int starts[BK + 1];
    __shared__ float adb[BK];

    const int b = blockIdx.x;
    const int t = threadIdx.x;
    const int lane = t & 63, wave = t >> 6;
    const int g0 = b * BK;
    const int row0 = g0;

    if (t < BK) {
        sm.a.hist[t] = 0;
        adb[t] = (g0 + t < n) ? adA[g0 + t] : 0.f;
    }
    __syncthreads();

    int cnt = bcur[b];
    if (cnt > CAP) cnt = CAP;
    unsigned* eb = ebuf + (size_t)b * CAP;

    unsigned c[3];
#pragma unroll
    for (int k = 0; k < 3; ++k) {
        const int i = t + k * 512;
        if (i < cnt) { c[k] = eb[i]; atomicAdd(&sm.a.hist[c[k] & 63], 1); }
    }
    __syncthreads();
    if (wave == 0) {
        int v = sm.a.hist[lane];
#pragma unroll
        for (int o = 1; o < 64; o <<= 1) {
            const int u = __shfl_up(v, o);
            if (lane >= o) v += u;
        }
        starts[lane + 1] = v;
        sm.a.cur[lane] = v - sm.a.hist[lane];
        if (lane == 0) starts[0] = 0;
    }
    __syncthreads();
#pragma unroll
    for (int k = 0; k < 3; ++k) {
        const int i = t + k * 512;
        if (i < cnt) { const int p = atomicAdd(&sm.a.cur[c[k] & 63], 1); sm.a.scode[p] = c[k]; }
    }
    __syncthreads();

    unsigned cc[3]; float vv[3];
#pragma unroll
    for (int k = 0; k < 3; ++k) {
        const int i = t + k * 512;
        if (i < cnt) { cc[k] = sm.a.scode[i]; eb[i] = cc[k]; vv[k] = asA[cc[k] >> 6]; }
    }
    if (t <= BK) startsG[b * (BK + 1) + t] = starts[t];
#pragma unroll
    for (int k = 0; k < 3; ++k) {
        const int i = t + k * 512;
        if (i < cnt) {
            float tt = vv[k] + adb[cc[k] & 63];
            tt = (tt >= 0.f) ? tt : 0.2f * tt;
            sm.a.sw[i] = __expf(tt);
        }
    }
    __syncthreads();

    agg_phaseB_to(sm.a.scode, sm.a.sw, starts, adb, asA, xphA, b1,
                  &htile[0][0], 68, g0, n);
    __syncthreads();

    if (t < 64) sm.g.asl[t] = asrc2[t];
    else if (t < 128) sm.g.adl[t - 64] = adst2[t - 64];

    for (int i = t; i < 64 * 16; i += 512) {
        const int r = i >> 4, c4 = (i & 15) << 2;
        const float4 v = *(const float4*)(&htile[r][c4]);
        sm.g.Xs[r][c4 + 0] = (f16)v.x; sm.g.Xs[r][c4 + 1] = (f16)v.y;
        sm.g.Xs[r][c4 + 2] = (f16)v.z; sm.g.Xs[r][c4 + 3] = (f16)v.w;
    }
    for (int i = t; i < 64 * 16; i += 512) {
        const int k = i >> 4, c4 = (i & 15) << 2;
        const float4 v = *(const float4*)(W2 + k * FEAT + c4);
        sm.g.Wt[c4 + 0][k] = (f16)v.x; sm.g.Wt[c4 + 1][k] = (f16)v.y;
        sm.g.Wt[c4 + 2][k] = (f16)v.z; sm.g.Wt[c4 + 3][k] = (f16)v.w;
    }
    __syncthreads();

    f32x4 acc[4];
    if (wave < 4) {
        const int mrow = (wave << 4) + (lane & 15);
        const int kg = lane >> 4;
        const f16x8 a0 = *(const f16x8*)(&sm.g.Xs[mrow][kg * 8]);
        const f16x8 a1 = *(const f16x8*)(&sm.g.Xs[mrow][32 + kg * 8]);
#pragma unroll
        for (int nt = 0; nt < 4; ++nt) {
            const int ncol = nt * 16 + (lane & 15);
            const f16x8 b0 = *(const f16x8*)(&sm.g.Wt[ncol][kg * 8]);
            const f16x8 b1v = *(const f16x8*)(&sm.g.Wt[ncol][32 + kg * 8]);
            f32x4 cacc = {0.f, 0.f, 0.f, 0.f};
            cacc = __builtin_amdgcn_mfma_f32_16x16x32_f16(a0, b0, cacc, 0, 0, 0);
            cacc = __builtin_amdgcn_mfma_f32_16x16x32_f16(a1, b1v, cacc, 0, 0, 0);
            acc[nt] = cacc;
        }
    }
    __syncthreads();
    if (wave < 4) {
#pragma unroll
        for (int nt = 0; nt < 4; ++nt)
#pragma unroll
            for (int reg = 0; reg < 4; ++reg)
                sm.g.Cs[wave][(lane >> 4) * 4 + reg][nt * 16 + (lane & 15)] = acc[nt][reg];
    }
    __syncthreads();

    for (int i = t; i < 64 * 32; i += 512) {
        const int r = i >> 5, fp = i & 31;
        const int node = row0 + r;
        if (node < n) {
            const __half2 pk = __floats2half2_rn(sm.g.Cs[r >> 4][r & 15][2 * fp],
                                                 sm.g.Cs[r >> 4][r & 15][2 * fp + 1]);
            xphB[(size_t)node * 32 + fp] = *(const unsigned*)&pk;
        }
    }
    if (t < 256) {
        const int r = t >> 2, q = t & 3;
        float s1 = 0.f, s2 = 0.f;
#pragma unroll
        for (int j = 0; j < 16; ++j) {
            const int cidx = q * 16 + j;
            const float v = sm.g.Cs[r >> 4][r & 15][cidx];
            s1 += v * sm.g.asl[cidx];
            s2 += v * sm.g.adl[cidx];
        }
        s1 += __shfl_xor(s1, 1); s1 += __shfl_xor(s1, 2);
        s2 += __shfl_xor(s2, 1); s2 += __shfl_xor(s2, 2);
        const int node = row0 + r;
        if (q == 0 && node < n) { asB[node] = s1; adB[node] = s2; }
    }
}

// ---------------------------------------------------------------------------
// D3: layer-2 aggregate FUSED with pooling (per-bucket per-graph partials;
// batch sorted, <=2 graphs per 64-node bucket; lane-exclusive LDS slots).
// No fences — D4 reads gpart after the dispatch boundary.
// ---------------------------------------------------------------------------
__global__ __launch_bounds__(512) void agg2_pool_kernel(
    const unsigned* __restrict__ ebuf, const int* __restrict__ startsG,
    const float* __restrict__ as_, const float* __restrict__ ad_,
    const uint4* __restrict__ xph4, const float* __restrict__ bias,
    const int* __restrict__ batch, float* __restrict__ gpart,
    float* __restrict__ osum, int n)
{
    __shared__ unsigned scode[CAP];
    __shared__ float    sw[CAP];
    __shared__ int startsL[BK + 1];
    __shared__ float adb[BK];
    __shared__ int batchL[BK];
    __shared__ float gpartW[8][2][LG][FEAT];   // 16 KB, lane-exclusive slots

    const int b = blockIdx.x;
    const int t = threadIdx.x;
    const int lane = t & 63, wave = t >> 6;
    const int g0 = b * BK;

    if (t < BK) {
        const int g = g0 + t;
        adb[t] = (g < n) ? ad_[g] : 0.f;
        batchL[t] = batch[(g < n) ? g : (n - 1)];
    }
    if (t <= BK) startsL[t] = startsG[b * (BK + 1) + t];
    for (int i = t; i < 8 * 2 * LG * FEAT; i += 512) ((float*)gpartW)[i] = 0.f;
    __syncthreads();

    const int cnt = startsL[BK];
    const unsigned* eb = ebuf + (size_t)b * CAP;

    unsigned cc[3]; float vv[3];
#pragma unroll
    for (int k = 0; k < 3; ++k) {
        const int i = t + k * 512;
        if (i < cnt) { cc[k] = eb[i]; vv[k] = as_[cc[k] >> 6]; }
    }
#pragma unroll
    for (int k = 0; k < 3; ++k) {
        const int i = t + k * 512;
        if (i < cnt) {
            float tt = vv[k] + adb[cc[k] & 63];
            tt = (tt >= 0.f) ? tt : 0.2f * tt;
            scode[i] = cc[k]; sw[i] = __expf(tt);
        }
    }
    __syncthreads();

    const int np = lane >> 5;
    const int q  = (lane >> 3) & 3;
    const int fo = lane & 7;
    const int gbase = batchL[0];

    for (int pair = wave; pair < BK / 2; pair += 8) {
        const int node = pair * 2 + np;
        const int g = g0 + node;
        const int gc = (g < n) ? g : (n - 1);
        const int st = startsL[node], en = startsL[node + 1];

        float a[8] = {0.f, 0.f, 0.f, 0.f, 0.f, 0.f, 0.f, 0.f};
        float wsum = 0.f;

        int i = st + q;
        for (; i + 12 < en; i += 16) {
            const unsigned c0 = scode[i];
            const unsigned c1 = scode[i + 4];
            const unsigned c2 = scode[i + 8];
            const unsigned c3 = scode[i + 12];
            const float w0 = sw[i], w1 = sw[i + 4], w2 = sw[i + 8], w3 = sw[i + 12];
            const uint4 x0 = xph4[(size_t)(c0 >> 6) * 8 + fo];
            const uint4 x1 = xph4[(size_t)(c1 >> 6) * 8 + fo];
            const uint4 x2 = xph4[(size_t)(c2 >> 6) * 8 + fo];
            const uint4 x3 = xph4[(size_t)(c3 >> 6) * 8 + fo];
#pragma unroll
            for (int u = 0; u < 4; ++u) {
                const uint4 xv = (u == 0) ? x0 : (u == 1) ? x1 : (u == 2) ? x2 : x3;
                const float wv = (u == 0) ? w0 : (u == 1) ? w1 : (u == 2) ? w2 : w3;
                const __half2 p0 = *(const __half2*)&xv.x;
                const __half2 p1 = *(const __half2*)&xv.y;
                const __half2 p2 = *(const __half2*)&xv.z;
                const __half2 p3 = *(const __half2*)&xv.w;
                a[0] += wv * __low2float(p0);  a[1] += wv * __high2float(p0);
                a[2] += wv * __low2float(p1);  a[3] += wv * __high2float(p1);
                a[4] += wv * __low2float(p2);  a[5] += wv * __high2float(p2);
                a[6] += wv * __low2float(p3);  a[7] += wv * __high2float(p3);
            }
            wsum += (w0 + w1) + (w2 + w3);
        }
        for (; i < en; i += 4) {
            const unsigned c0 = scode[i];
            const float w0 = sw[i];
            const uint4 xv = xph4[(size_t)(c0 >> 6) * 8 + fo];
            const __half2 p0 = *(const __half2*)&xv.x;
            const __half2 p1 = *(const __half2*)&xv.y;
            const __half2 p2 = *(const __half2*)&xv.z;
            const __half2 p3 = *(const __half2*)&xv.w;
            a[0] += w0 * __low2float(p0);  a[1] += w0 * __high2float(p0);
            a[2] += w0 * __low2float(p1);  a[3] += w0 * __high2float(p1);
            a[4] += w0 * __low2float(p2);  a[5] += w0 * __high2float(p2);
            a[6] += w0 * __low2float(p3);  a[7] += w0 * __high2float(p3);
            wsum += w0;
        }

#pragma unroll
        for (int j = 0; j < 8; ++j) {
            a[j] += __shfl_xor(a[j], 8);
            a[j] += __shfl_xor(a[j], 16);
        }
        wsum += __shfl_xor(wsum, 8);
        wsum += __shfl_xor(wsum, 16);

        float tt = as_[gc] + adb[node];
        tt = (tt >= 0.f) ? tt : 0.2f * tt;
        const float wself = __expf(tt);
        const uint4 xg = xph4[(size_t)gc * 8 + fo];
        const __half2 s0 = *(const __half2*)&xg.x;
        const __half2 s1 = *(const __half2*)&xg.y;
        const __half2 s2 = *(const __half2*)&xg.z;
        const __half2 s3 = *(const __half2*)&xg.w;
        const float dinv = 1.f / (wsum + wself);
        const float4 bA = *(const float4*)(bias + 8 * fo);
        const float4 bB = *(const float4*)(bias + 8 * fo + 4);

        if (q == 0 && g < n) {
            float4 vA, vB;
            vA.x = fmaxf((a[0] + wself * __low2float(s0))  * dinv + bA.x, 0.f);
            vA.y = fmaxf((a[1] + wself * __high2float(s0)) * dinv + bA.y, 0.f);
            vA.z = fmaxf((a[2] + wself * __low2float(s1))  * dinv + bA.z, 0.f);
            vA.w = fmaxf((a[3] + wself * __high2float(s1)) * dinv + bA.w, 0.f);
            vB.x = fmaxf((a[4] + wself * __low2float(s2))  * dinv + bB.x, 0.f);
            vB.y = fmaxf((a[5] + wself * __high2float(s2)) * dinv + bB.y, 0.f);
            vB.z = fmaxf((a[6] + wself * __low2float(s3))  * dinv + bB.z, 0.f);
            vB.w = fmaxf((a[7] + wself * __high2float(s3)) * dinv + bB.w, 0.f);

            const int lg = batchL[node] - gbase;
            if (lg < LG) {
                float* p = &gpartW[wave][np][lg][8 * fo];
                float4 oA = *(float4*)p;
                float4 oB = *(float4*)(p + 4);
                oA.x += vA.x; oA.y += vA.y; oA.z += vA.z; oA.w += vA.w;
                oB.x += vB.x; oB.y += vB.y; oB.z += vB.z; oB.w += vB.w;
                *(float4*)p = oA;
                *(float4*)(p + 4) = oB;
            } else {
                float* o = osum + (size_t)batchL[node] * FEAT + 8 * fo;
                atomicAdd(o + 0, vA.x); atomicAdd(o + 1, vA.y);
                atomicAdd(o + 2, vA.z); atomicAdd(o + 3, vA.w);
                atomicAdd(o + 4, vB.x); atomicAdd(o + 5, vB.y);
                atomicAdd(o + 6, vB.z); atomicAdd(o + 7, vB.w);
            }
        }
    }
    __syncthreads();

    if (t < LG * FEAT) {
        const int lg = t >> 6, f = t & 63;
        float s = 0.f;
#pragma unroll
        for (int w = 0; w < 8; ++w)
            s += gpartW[w][0][lg][f] + gpartW[w][1][lg][f];
        gpart[((size_t)b * LG + lg) * FEAT + f] = s;
    }
}

// ---------------------------------------------------------------------------
// D4: pool reduce — graph g sums partials from its ~7 covering buckets.
// ---------------------------------------------------------------------------
__device__ __forceinline__ int lower_bound_i(const int* a, int n, int key)
{
    int lo = 0, hi = n;
    while (lo < hi) {
        const int mid = (lo + hi) >> 1;
        if (a[mid] < key) lo = mid + 1; else hi = mid;
    }
    return lo;
}

__global__ __launch_bounds__(64) void pool_reduce_kernel(
    const float* __restrict__ gpart, const float* __restrict__ osum,
    const int* __restrict__ batch, float* __restrict__ out, int n, int G)
{
    const int g = blockIdx.x;
    const int lane = threadIdx.x;

    const int lo = lower_bound_i(batch, n, g);
    const int hi = lower_bound_i(batch, n, g + 1);

    float s = osum[(size_t)g * FEAT + lane];
    if (lo < hi) {
        const int b0 = lo >> 6, b1 = (hi - 1) >> 6;
        for (int b = b0; b <= b1; ++b) {
            const int base = batch[b << 6];
            const int lg = g - base;
            if (lg >= 0 && lg < LG)
                s += gpart[((size_t)b * LG + lg) * FEAT + lane];
        }
    }
    out[(size_t)g * FEAT + lane] = s / fmaxf((float)(hi - lo), 1.f);
}

extern "C" void kernel_launch(void* const* d_in, const int* in_sizes, int n_in,
                              void* d_out, int out_size, void* d_ws, size_t ws_size,
                              hipStream_t stream)
{
    const float* x      = (const float*)d_in[0];
    const int*   ei     = (const int*)d_in[1];
    const int*   batch  = (const int*)d_in[2];
    const float* W1     = (const float*)d_in[3];
    const float* asrc1  = (const float*)d_in[4];
    const float* adst1  = (const float*)d_in[5];
    const float* b1     = (const float*)d_in[6];
    const float* W2     = (const float*)d_in[7];
    const float* asrc2  = (const float*)d_in[8];
    const float* adst2  = (const float*)d_in[9];
    const float* b2     = (const float*)d_in[10];

    const int N = in_sizes[2];          // 50000 nodes
    const int E = in_sizes[1] / 2;      // 800000 edges
    const int G = out_size / FEAT;      // 128 graphs

    const int* src = ei;
    const int* dst = ei + E;

    const int nbuck   = (N + BK - 1) / BK;                  // 782
    const int nchunks = (E + CHUNK - 1) / CHUNK;            // 196
    const int gemmBlocks = (N + 63) / 64;                   // 782

    // Workspace layout (bcur|osum adjacent -> one memset)
    unsigned* xphA    = (unsigned*)d_ws;                     // N*32 u32
    unsigned* xphB    = xphA + (size_t)N * 32;               // N*32 u32
    float*    asA     = (float*)(xphB + (size_t)N * 32);     // N f
    float*    adA     = asA + N;                             // N f
    float*    asB     = adA + N;                             // N f
    float*    adB     = asB + N;                             // N f
    int*      bcur    = (int*)(adB + N);                     // nbuck i
    float*    osum    = (float*)(bcur + nbuck);              // G*64 f (fallback)
    unsigned* ebuf    = (unsigned*)(osum + (size_t)G * FEAT);// nbuck*CAP u32
    int*      startsG = (int*)(ebuf + (size_t)nbuck * CAP);  // nbuck*(BK+1) i
    float*    gpart   = (float*)(startsG + nbuck * (BK + 1));// nbuck*LG*64 f

    // D0: zero bucket cursors + osum fallback (contiguous)
    hipMemsetAsync(bcur, 0,
                   (size_t)nbuck * sizeof(int) + (size_t)G * FEAT * sizeof(float),
                   stream);
    // D1: scatter (LDS-staged coalesced writes) || gemm layer 1
    scatter_gemm1_kernel<<<nchunks + gemmBlocks, 256, 0, stream>>>(
        src, dst, bcur, ebuf, x, W1, asrc1, adst1, xphA, asA, adA,
        N, E, nbuck, nchunks);
    // D2: sort + layer-1 aggregate (LDS h-tile) + layer-2 gemm (tile-aligned)
    sortagg1_gemm2_kernel<<<nbuck, 512, 0, stream>>>(
        bcur, ebuf, startsG, asA, adA, (const uint4*)xphA, b1,
        W2, asrc2, adst2, xphB, asB, adB, N);
    // D3: layer-2 aggregate fused with per-bucket graph-partial pooling
    agg2_pool_kernel<<<nbuck, 512, 0, stream>>>(
        ebuf, startsG, asB, adB, (const uint4*)xphB, b2,
        batch, gpart, osum, N);
    // D4: pool reduce (tiny)
    pool_reduce_kernel<<<G, 64, 0, stream>>>(gpart, osum, batch,
                                             (float*)d_out, N, G);
}